// Round 14
// baseline (250.117 us; speedup 1.0000x reference)
//
#include <hip/hip_runtime.h>

#define NN 50000
#define EE 800000
#define LDK 136
#define SLOTS 64   // esrc slots per node (deg>SLOTS -> k_agg slow path)
#define FEPT 8     // edges per thread in fill
#define NFA 157    // fill blocks fused into k_convfill: edges [0, NFA*2048)
#define SPLITE (NFA * 256 * FEPT)          // 321536
#define NFB 234    // fill blocks fused into k_projfill: edges [SPLITE, EE)
#define CONVB 2048 // convert blocks

// canonical bf16 region: element offsets
#define C_X    0
#define C_ZW   6400000   // zwt[c*128+d] = fc_w[c>>4][d][c&15]
#define C_AL   6416384
#define C_AR   6416512
#define C_LNG  6416640
#define C_LNB  6416768
#define C_W1T  6416896   // w1t[n*128+k] = w1[k*512+n]
#define C_B1   6482432
#define C_W2T  6482944   // w2t[n*512+k] = w2[k*128+n]
#define C_B2   6548480
#define C_WAT  6548608   // wat[c*128+d]: c<8 -> fc_w[c]@a_l[c], c>=8 -> fc_w[c-8]@a_r[c-8]
#define C_TOT  6550656

typedef __attribute__((ext_vector_type(8))) short bf16x8;
typedef __attribute__((ext_vector_type(4))) float f32x4;

__device__ __forceinline__ float bf2f(unsigned short u) {
  union { unsigned int i; float f; } v; v.i = ((unsigned int)u) << 16; return v.f;
}
__device__ __forceinline__ unsigned short f2bf(float f) {
  union { float f; unsigned int i; } v; v.f = f;
  unsigned int r = v.i + 0x7fffu + ((v.i >> 16) & 1u);
  return (unsigned short)(r >> 16);
}
__device__ __forceinline__ int ld_idx(const void* p, int i, int is64) {
  return is64 ? (int)((const long long*)p)[i] : ((const int*)p)[i];
}

// exact-form gelu via A&S 7.1.26 erf approx (|err| <= 1.5e-7, branchless).
__device__ __forceinline__ float fast_gelu(float u) {
  float ax = fabsf(u) * 0.70710678118654752f;
  float d  = fmaf(0.3275911f, ax, 1.f);
  float r  = __builtin_amdgcn_rcpf(d);
  r = r * fmaf(-d, r, 2.f);
  float p = fmaf(1.061405429f, r, -1.453152027f);
  p = fmaf(p, r, 1.421413741f);
  p = fmaf(p, r, -0.284496736f);
  p = fmaf(p, r, 0.254829592f);
  p = p * r;
  float e = __expf(-ax * ax);
  float erfv = fmaf(-p, e, 1.f);
  union { float f; unsigned int i; } su, se;
  su.f = u; se.f = erfv;
  se.i = se.i | (su.i & 0x80000000u);
  return 0.5f * u * (1.f + se.f);
}

// ---- merged dtype probes: flags[0,1]=x float probe, flags[2,3]=src/dst widths ----
__global__ void k_probe(const unsigned short* __restrict__ xr,
                        const int* __restrict__ s, const int* __restrict__ d,
                        int* __restrict__ flags) {
  int i = blockIdx.x * 256 + threadIdx.x;
  int bad = 0, zc = 0, zs = 0, zd = 0;
  for (int j = i; j < 65536; j += 32 * 256) {
    unsigned short u = xr[j];
    if ((u & 0x7F80u) == 0x7F80u) bad = 1;
    if (((j & 1) == 0) && u == 0) zc++;
  }
  for (int j = i; j < 131072; j += 32 * 256) {
    if (j & 1) {
      if (s[j] == 0) zs++;
      if (d[j] == 0) zd++;
    }
  }
  if (bad) atomicOr(&flags[0], 1);
  if (zc) atomicAdd(&flags[1], zc);
  if (zs) atomicAdd(&flags[2], zs);
  if (zd) atomicAdd(&flags[3], zd);
}

// ---- strided-slot fill body: FEPT edges starting at base ----
__device__ __forceinline__ void do_fill(const void* __restrict__ src,
                                        const void* __restrict__ dst,
                                        const int* __restrict__ iflags,
                                        int* __restrict__ cnt,
                                        unsigned short* __restrict__ esrc,
                                        int base) {
  if (base >= EE) return;
  const int s64 = iflags[0] > 1000, d64 = iflags[1] > 1000;
  int dv[FEPT], sv[FEPT];
  if (!d64 && base + FEPT <= EE) {
    const int4* p = (const int4*)((const int*)dst + base);
    int4 a = p[0], b = p[1];
    dv[0]=a.x; dv[1]=a.y; dv[2]=a.z; dv[3]=a.w; dv[4]=b.x; dv[5]=b.y; dv[6]=b.z; dv[7]=b.w;
  } else {
#pragma unroll
    for (int j = 0; j < FEPT; j++) dv[j] = (base + j < EE) ? ld_idx(dst, base + j, d64) : 0;
  }
  if (!s64 && base + FEPT <= EE) {
    const int4* p = (const int4*)((const int*)src + base);
    int4 a = p[0], b = p[1];
    sv[0]=a.x; sv[1]=a.y; sv[2]=a.z; sv[3]=a.w; sv[4]=b.x; sv[5]=b.y; sv[6]=b.z; sv[7]=b.w;
  } else {
#pragma unroll
    for (int j = 0; j < FEPT; j++) sv[j] = (base + j < EE) ? ld_idx(src, base + j, s64) : 0;
  }
#pragma unroll
  for (int j = 0; j < FEPT; j++) {
    if (base + j < EE) {
      unsigned d = (unsigned)dv[j]; if (d >= NN) d = 0;
      unsigned s = (unsigned)sv[j]; if (s >= NN) s = 0;
      int p = atomicAdd(&cnt[d], 1);
      if (p < SLOTS) esrc[d * SLOTS + p] = (unsigned short)s;
    }
  }
}

// ---- fused: canonicalize (bf16 canon + transposes + wat) ∥ fill edges [0,SPLITE) ----
__global__ __launch_bounds__(256) void k_convfill(
    const void* __restrict__ x, const void* __restrict__ fcw,
    const void* __restrict__ a_l, const void* __restrict__ a_r,
    const void* __restrict__ lng, const void* __restrict__ lnb,
    const void* __restrict__ w1, const void* __restrict__ b1,
    const void* __restrict__ w2, const void* __restrict__ b2,
    const int* __restrict__ flags, unsigned short* __restrict__ canon,
    const void* __restrict__ srcp, const void* __restrict__ dstp,
    int* __restrict__ cnt, unsigned short* __restrict__ esrc) {
  if (blockIdx.x < NFA) {
    do_fill(srcp, dstp, flags + 2, cnt, esrc, (blockIdx.x * 256 + threadIdx.x) * FEPT);
    return;
  }
  const int isf32 = (flags[0] != 0) || (flags[1] > 8192);
  const int tid0 = (blockIdx.x - NFA) * 256 + threadIdx.x;
  // phase 1: x region, vectorized 8 elems/iter
  for (int v = tid0; v < (C_ZW >> 3); v += CONVB * 256) {
    if (isf32) {
      const float* xf = (const float*)x + v * 8;
      float4 a = *(const float4*)xf;
      float4 b = *(const float4*)(xf + 4);
      union { unsigned short u[8]; uint4 q; } pk;
      pk.u[0] = f2bf(a.x); pk.u[1] = f2bf(a.y); pk.u[2] = f2bf(a.z); pk.u[3] = f2bf(a.w);
      pk.u[4] = f2bf(b.x); pk.u[5] = f2bf(b.y); pk.u[6] = f2bf(b.z); pk.u[7] = f2bf(b.w);
      *(uint4*)(canon + v * 8) = pk.q;
    } else {
      *(uint4*)(canon + v * 8) = *(const uint4*)((const unsigned short*)x + v * 8);
    }
  }
  // phase 2: weight/bias regions (scalar) + wat fused projection vectors
  for (int i = C_ZW + tid0; i < C_TOT; i += CONVB * 256) {
    unsigned short v;
    if (i >= C_WAT) {
      int j = i - C_WAT; int c = j >> 7, dd = j & 127; int h = c & 7;
      const void* fa = (c < 8) ? a_l : a_r;
      float s = 0.f;
      if (isf32) {
        const float* fw = (const float*)fcw + h * 2048 + dd * 16;
        const float* fv = (const float*)fa + h * 16;
#pragma unroll
        for (int o = 0; o < 16; o++) s += fw[o] * fv[o];
      } else {
        const unsigned short* fw = (const unsigned short*)fcw + h * 2048 + dd * 16;
        const unsigned short* fv = (const unsigned short*)fa + h * 16;
#pragma unroll
        for (int o = 0; o < 16; o++) s += bf2f(fw[o]) * bf2f(fv[o]);
      }
      v = f2bf(s);
    } else {
      const void* src; int idx;
      if (i < C_AL)       { int j = i - C_ZW; int c = j >> 7, d = j & 127; src = fcw; idx = (c >> 4) * 2048 + d * 16 + (c & 15); }
      else if (i < C_AR)  { src = a_l; idx = i - C_AL; }
      else if (i < C_LNG) { src = a_r; idx = i - C_AR; }
      else if (i < C_LNB) { src = lng; idx = i - C_LNG; }
      else if (i < C_W1T) { src = lnb; idx = i - C_LNB; }
      else if (i < C_B1)  { int j = i - C_W1T; int n = j >> 7, k = j & 127; src = w1; idx = k * 512 + n; }
      else if (i < C_W2T) { src = b1;  idx = i - C_B1; }
      else if (i < C_B2)  { int j = i - C_W2T; int n = j >> 9, k = j & 511; src = w2; idx = k * 128 + n; }
      else                { src = b2;  idx = i - C_B2; }
      if (isf32) v = f2bf(((const float*)src)[idx]);
      else       v = ((const unsigned short*)src)[idx];
    }
    canon[i] = v;
  }
}

// ---- fused: projection z = x@W (MFMA) + el/er via wat ∥ fill edges [SPLITE,EE) ----
__global__ __launch_bounds__(256) void k_projfill(
    const unsigned short* __restrict__ canon,
    unsigned short* __restrict__ z, float* __restrict__ el, float* __restrict__ er,
    const void* __restrict__ srcp, const void* __restrict__ dstp,
    const int* __restrict__ iflags,
    int* __restrict__ cnt, unsigned short* __restrict__ esrc) {
  __shared__ unsigned short sA[128 * LDK];
  __shared__ unsigned short sB[64 * LDK];
  if (blockIdx.x < NFB) {
    do_fill(srcp, dstp, iflags, cnt, esrc,
            SPLITE + (blockIdx.x * 256 + threadIdx.x) * FEPT);
    return;
  }
  const int pid = blockIdx.x - NFB;
  const unsigned short* xc  = canon + C_X;
  const unsigned short* zwt = canon + C_ZW;
  const unsigned short* wat = canon + C_WAT;
  const int tid = threadIdx.x;
  const int row0 = (pid >> 1) * 128;
  const int n0 = (pid & 1) * 64;
  for (int v = tid; v < 2048; v += 256) {
    int r = v >> 4, k8 = (v & 15) << 3;
    int gr = row0 + r; if (gr >= NN) gr = NN - 1;
    *(uint4*)(&sA[r * LDK + k8]) = *(const uint4*)(xc + gr * 128 + k8);
  }
  for (int v = tid; v < 1024; v += 256) {
    int n = v >> 4, k8 = (v & 15) << 3;
    *(uint4*)(&sB[n * LDK + k8]) = *(const uint4*)(zwt + (n0 + n) * 128 + k8);
  }
  __syncthreads();
  const int lane = tid & 63, w = tid >> 6;
  const int mr = lane & 15, q = lane >> 4;
  const f32x4 zero = {0.f, 0.f, 0.f, 0.f};
  f32x4 acc[8];
#pragma unroll
  for (int i = 0; i < 8; i++) acc[i] = zero;
#pragma unroll
  for (int kc = 0; kc < 4; kc++) {
    bf16x8 b = *(const bf16x8*)(&sB[(w * 16 + mr) * LDK + kc * 32 + q * 8]);
#pragma unroll
    for (int mt = 0; mt < 8; mt++) {
      bf16x8 a = *(const bf16x8*)(&sA[(mt * 16 + mr) * LDK + kc * 32 + q * 8]);
      acc[mt] = __builtin_amdgcn_mfma_f32_16x16x32_bf16(a, b, acc[mt], 0, 0, 0);
    }
  }
  const int col = n0 + w * 16 + mr;
#pragma unroll
  for (int mt = 0; mt < 8; mt++) {
#pragma unroll
    for (int r = 0; r < 4; r++) {
      int grow = row0 + mt * 16 + q * 4 + r;
      if (grow < NN) z[grow * 128 + col] = f2bf(acc[mt][r]);
    }
  }
  // el/er: 16 extra cols, computed once per row-tile by the half-0 block.
  // wave w covers row-tiles {w, w+4}.
  if (n0 == 0) {
    f32x4 e0 = zero, e1 = zero;
#pragma unroll
    for (int kc = 0; kc < 4; kc++) {
      bf16x8 b = *(const bf16x8*)(wat + mr * 128 + kc * 32 + q * 8);
      bf16x8 a0 = *(const bf16x8*)(&sA[(w * 16 + mr) * LDK + kc * 32 + q * 8]);
      bf16x8 a1 = *(const bf16x8*)(&sA[((w + 4) * 16 + mr) * LDK + kc * 32 + q * 8]);
      e0 = __builtin_amdgcn_mfma_f32_16x16x32_bf16(a0, b, e0, 0, 0, 0);
      e1 = __builtin_amdgcn_mfma_f32_16x16x32_bf16(a1, b, e1, 0, 0, 0);
    }
    float* eo = (mr < 8) ? el : er;
    const int hh = mr & 7;
#pragma unroll
    for (int r = 0; r < 4; r++) {
      int g0 = row0 + w * 16 + q * 4 + r;
      int g1 = row0 + (w + 4) * 16 + q * 4 + r;
      if (g0 < NN) eo[g0 * 8 + hh] = e0[r];
      if (g1 < NN) eo[g1 * 8 + hh] = e1[r];
    }
  }
}

// ---- wave-per-node: softmax + aggregate + elu + residual -> h1 fp32 (d_out) ----
// Round-9 proven two-pass form. Also computes LN stats into mars for k_ffn.
__global__ __launch_bounds__(256) void k_agg(
    const unsigned short* __restrict__ canon, const unsigned short* __restrict__ z,
    const float* __restrict__ el, const float* __restrict__ er,
    const int* __restrict__ cnt, const unsigned short* __restrict__ esrc,
    const void* __restrict__ srcp, const void* __restrict__ dstp,
    const int* __restrict__ iflags,
    float* __restrict__ h1out, float2* __restrict__ mars) {
  const unsigned short* xc = canon + C_X;
  const int lane = threadIdx.x & 63;
  const int node = blockIdx.x * 4 + (threadIdx.x >> 6);
  if (node >= NN) return;
  const int degr = cnt[node];
  const int hl = lane & 7;   // head owned by this lane
  const int g  = lane >> 3;  // edge subgroup
  const float ern = er[node * 8 + hl];

  float m = -3.0e38f;
  float acc[16];
#pragma unroll
  for (int j = 0; j < 16; j++) acc[j] = 0.f;
  float denom = 0.f;

  if (degr <= SLOTS) {
    const int deg = degr;
    const unsigned short* eptr = esrc + node * SLOTS;
    // ---- pass 1: per-head max, 16 edges in flight ----
    for (int b = 0; b < deg; b += 16) {
      int e0 = b + g, e1 = b + g + 8;
      int c0 = (e0 < deg) ? e0 : deg - 1;
      int c1 = (e1 < deg) ? e1 : deg - 1;
      unsigned s0 = eptr[c0]; if (s0 >= NN) s0 = 0;
      unsigned s1 = eptr[c1]; if (s1 >= NN) s1 = 0;
      float t0 = el[s0 * 8 + hl] + ern;
      float t1 = el[s1 * 8 + hl] + ern;
      t0 = (t0 > 0.f) ? t0 : 0.01f * t0;
      t1 = (t1 > 0.f) ? t1 : 0.01f * t1;
      if (e0 < deg) m = fmaxf(m, t0);
      if (e1 < deg) m = fmaxf(m, t1);
    }
    m = fmaxf(m, __shfl_xor(m, 8));
    m = fmaxf(m, __shfl_xor(m, 16));
    m = fmaxf(m, __shfl_xor(m, 32));
    // ---- pass 2: weighted aggregation, 16 edges in flight ----
    for (int b = 0; b < deg; b += 16) {
      int e0 = b + g, e1 = b + g + 8;
      int c0 = (e0 < deg) ? e0 : deg - 1;
      int c1 = (e1 < deg) ? e1 : deg - 1;
      unsigned s0 = eptr[c0]; if (s0 >= NN) s0 = 0;
      unsigned s1 = eptr[c1]; if (s1 >= NN) s1 = 0;
      float t0 = el[s0 * 8 + hl] + ern;
      float t1 = el[s1 * 8 + hl] + ern;
      bf16x8 za0 = *(const bf16x8*)(z + s0 * 128 + hl * 16);
      bf16x8 za1 = *(const bf16x8*)(z + s0 * 128 + hl * 16 + 8);
      bf16x8 zb0 = *(const bf16x8*)(z + s1 * 128 + hl * 16);
      bf16x8 zb1 = *(const bf16x8*)(z + s1 * 128 + hl * 16 + 8);
      t0 = (t0 > 0.f) ? t0 : 0.01f * t0;
      t1 = (t1 > 0.f) ? t1 : 0.01f * t1;
      float ex0 = (e0 < deg) ? __expf(fminf(t0 - m, 0.f)) : 0.f;
      float ex1 = (e1 < deg) ? __expf(fminf(t1 - m, 0.f)) : 0.f;
      denom += ex0 + ex1;
#pragma unroll
      for (int j = 0; j < 8; j++) {
        acc[j]     += ex0 * bf2f((unsigned short)za0[j]) + ex1 * bf2f((unsigned short)zb0[j]);
        acc[j + 8] += ex0 * bf2f((unsigned short)za1[j]) + ex1 * bf2f((unsigned short)zb1[j]);
      }
    }
  } else {
    // ---- slow path (deg > SLOTS; statistically unreachable, kept for correctness):
    // rescan ALL raw edges, filter dst == node. 8 edges in flight.
    const int s64 = iflags[0] > 1000, d64 = iflags[1] > 1000;
    for (int b = 0; b < EE; b += 8) {
      int e = b + g;
      unsigned dd = (unsigned)ld_idx(dstp, e, d64); if (dd >= NN) dd = 0;
      bool ok = (dd == (unsigned)node);
      unsigned s0 = (unsigned)ld_idx(srcp, e, s64); if (s0 >= NN) s0 = 0;
      float t0 = el[s0 * 8 + hl] + ern;
      t0 = (t0 > 0.f) ? t0 : 0.01f * t0;
      if (ok) m = fmaxf(m, t0);
    }
    m = fmaxf(m, __shfl_xor(m, 8));
    m = fmaxf(m, __shfl_xor(m, 16));
    m = fmaxf(m, __shfl_xor(m, 32));
    for (int b = 0; b < EE; b += 8) {
      int e = b + g;
      unsigned dd = (unsigned)ld_idx(dstp, e, d64); if (dd >= NN) dd = 0;
      bool ok = (dd == (unsigned)node);
      unsigned s0 = (unsigned)ld_idx(srcp, e, s64); if (s0 >= NN) s0 = 0;
      float t0 = el[s0 * 8 + hl] + ern;
      t0 = (t0 > 0.f) ? t0 : 0.01f * t0;
      float ex0 = ok ? __expf(fminf(t0 - m, 0.f)) : 0.f;
      denom += ex0;
      bf16x8 za0 = *(const bf16x8*)(z + s0 * 128 + hl * 16);
      bf16x8 za1 = *(const bf16x8*)(z + s0 * 128 + hl * 16 + 8);
#pragma unroll
      for (int j = 0; j < 8; j++) {
        acc[j]     += ex0 * bf2f((unsigned short)za0[j]);
        acc[j + 8] += ex0 * bf2f((unsigned short)za1[j]);
      }
    }
  }

  // ---- denom reduce + cross-group reduce-scatter: 16->8->4->2 ----
  denom += __shfl_xor(denom, 8);
  denom += __shfl_xor(denom, 16);
  denom += __shfl_xor(denom, 32);
  {
    const bool hi1 = (lane & 32) != 0;   // g bit 2
#pragma unroll
    for (int j = 0; j < 8; j++) {
      float send = hi1 ? acc[j] : acc[j + 8];
      float recv = __shfl_xor(send, 32);
      float keep = hi1 ? acc[j + 8] : acc[j];
      acc[j] = keep + recv;
    }
    const bool hi2 = (lane & 16) != 0;   // g bit 1
#pragma unroll
    for (int j = 0; j < 4; j++) {
      float send = hi2 ? acc[j] : acc[j + 4];
      float recv = __shfl_xor(send, 16);
      float keep = hi2 ? acc[j + 4] : acc[j];
      acc[j] = keep + recv;
    }
    const bool hi3 = (lane & 8) != 0;    // g bit 0
#pragma unroll
    for (int j = 0; j < 2; j++) {
      float send = hi3 ? acc[j] : acc[j + 2];
      float recv = __shfl_xor(send, 8);
      float keep = hi3 ? acc[j + 2] : acc[j];
      acc[j] = keep + recv;
    }
  }
  // lane now holds cols c = hl*16 + g*2, +1 in acc[0], acc[1]
  const float inv = (denom > 0.f) ? 1.f / denom : 0.f;
  const int c = hl * 16 + g * 2;
  float r0 = acc[0] * inv;
  float r1 = acc[1] * inv;
  unsigned int xx = *(const unsigned int*)(xc + node * 128 + c);
  float hv0 = ((r0 > 0.f) ? r0 : (__expf(fminf(r0, 0.f)) - 1.f)) + bf2f((unsigned short)(xx & 0xffffu));
  float hv1 = ((r1 > 0.f) ? r1 : (__expf(fminf(r1, 0.f)) - 1.f)) + bf2f((unsigned short)(xx >> 16));
  // ---- LN stats: wave holds the full 128-col row ----
  float s1 = hv0 + hv1;
  float s2 = hv0 * hv0 + hv1 * hv1;
#pragma unroll
  for (int off = 1; off < 64; off <<= 1) {
    s1 += __shfl_xor(s1, off);
    s2 += __shfl_xor(s2, off);
  }
  if (lane == 0) {
    float mu = s1 * (1.f / 128.f);
    float var = s2 * (1.f / 128.f) - mu * mu;
    mars[node] = make_float2(mu, rsqrtf(fmaxf(var, 0.f) + 1e-6f));
  }
  *(float2*)(h1out + node * 128 + c) = make_float2(hv0, hv1);
}

// ---- fused FFN (MFMA): LN-apply -> gelu(ln@w1+b1)@w2 + b2 + h1 ----
// 128 rows/block, 1024 threads (16 waves = 8 col-groups x 2 row-halves),
// 4 K-quarters of 128 inter cols. LDS 69.6 KB -> 2 blocks/CU = 2048 thr (full);
// grid 391 <= 512 resident slots -> whole grid co-resident, no dispatch tail.
__global__ __launch_bounds__(1024) void k_ffn(
    const unsigned short* __restrict__ canon, const float2* __restrict__ mars,
    float* __restrict__ out) {
  const unsigned short* lngc = canon + C_LNG;
  const unsigned short* lnbc = canon + C_LNB;
  const unsigned short* w1t  = canon + C_W1T;
  const unsigned short* b1c  = canon + C_B1;
  const unsigned short* w2t  = canon + C_W2T;
  const unsigned short* b2c  = canon + C_B2;
  __shared__ unsigned short sLn[128 * LDK];   // 34816 B
  __shared__ unsigned short sInt[128 * LDK];  // 34816 B (total 69632)
  const int tid = threadIdx.x;
  const int row0 = blockIdx.x * 128;
  // ---- LN apply: 8 threads/row, 16 elems each (128 rows) ----
  {
    const int r = tid >> 3, t8 = tid & 7;
    const int grow = row0 + r;
    const int gr = (grow < NN) ? grow : NN - 1;
    const float2 ms = mars[gr];
    const float* hrow = out + (size_t)gr * 128 + t8 * 16;
#pragma unroll
    for (int h8 = 0; h8 < 2; h8++) {
      float4 a = *(const float4*)(hrow + h8 * 8);
      float4 b = *(const float4*)(hrow + h8 * 8 + 4);
      union { unsigned short u[8]; uint4 q; } gv, bv, pk;
      gv.q = *(const uint4*)(lngc + t8 * 16 + h8 * 8);
      bv.q = *(const uint4*)(lnbc + t8 * 16 + h8 * 8);
      float vv[8] = {a.x, a.y, a.z, a.w, b.x, b.y, b.z, b.w};
#pragma unroll
      for (int j = 0; j < 8; j++)
        pk.u[j] = f2bf((vv[j] - ms.x) * ms.y * bf2f(gv.u[j]) + bf2f(bv.u[j]));
      *(uint4*)(&sLn[r * LDK + t8 * 16 + h8 * 8]) = pk.q;
    }
  }
  __syncthreads();
  const int lane = tid & 63;
  const int w16 = tid >> 6;          // 0..15
  const int wc = w16 & 7;            // inter-col group
  const int wr = w16 >> 3;           // row half (0: rows 0-63, 1: rows 64-127)
  const int mr = lane & 15, q = lane >> 4;
  const f32x4 zero = {0.f, 0.f, 0.f, 0.f};
  f32x4 acc2[4];
#pragma unroll
  for (int a = 0; a < 4; a++) acc2[a] = zero;
#pragma unroll
  for (int qr = 0; qr < 4; qr++) {
    if (qr) __syncthreads();   // previous quarter's sInt readers done
    // ---- GEMM1 (swapped): wave (wc,wr) covers inter cols [qr*128 + wc*16, +16)
    //      over rows [wr*64, +64) ----
    const int colg = qr * 128 + wc * 16;
    f32x4 a1[4];
#pragma unroll
    for (int a = 0; a < 4; a++) a1[a] = zero;
#pragma unroll
    for (int kc = 0; kc < 4; kc++) {
      bf16x8 wf = *(const bf16x8*)(w1t + (colg + mr) * 128 + kc * 32 + q * 8);
#pragma unroll
      for (int rt = 0; rt < 4; rt++) {
        bf16x8 lf = *(const bf16x8*)(&sLn[(wr * 64 + rt * 16 + mr) * LDK + kc * 32 + q * 8]);
        a1[rt] = __builtin_amdgcn_mfma_f32_16x16x32_bf16(wf, lf, a1[rt], 0, 0, 0);
      }
    }
    // C[icol = colg + q*4 + r][row = wr*64 + rt*16 + mr]; sInt local col = wc*16 + q*4
    union { unsigned short u[4]; uint2 v; } b1v;
    b1v.v = *(const uint2*)(b1c + colg + q * 4);
#pragma unroll
    for (int rt = 0; rt < 4; rt++) {
      union { unsigned short u[4]; uint2 v; } pk;
#pragma unroll
      for (int r = 0; r < 4; r++)
        pk.u[r] = f2bf(fast_gelu(a1[rt][r] + bf2f(b1v.u[r])));
      *(uint2*)(&sInt[(wr * 64 + rt * 16 + mr) * LDK + wc * 16 + q * 4]) = pk.v;
    }
    __syncthreads();
    // ---- GEMM2: K-chunk [qr*128, +128), out col = wc*16 + mr, rows [wr*64,+64) ----
#pragma unroll
    for (int ks = 0; ks < 4; ks++) {
      bf16x8 bw = *(const bf16x8*)(w2t + (wc * 16 + mr) * 512 + qr * 128 + ks * 32 + q * 8);
#pragma unroll
      for (int mt = 0; mt < 4; mt++) {
        bf16x8 af = *(const bf16x8*)(&sInt[(wr * 64 + mt * 16 + mr) * LDK + ks * 32 + q * 8]);
        acc2[mt] = __builtin_amdgcn_mfma_f32_16x16x32_bf16(af, bw, acc2[mt], 0, 0, 0);
      }
    }
  }
  {
    const int col = wc * 16 + mr;
    const float bias = bf2f(b2c[col]);
#pragma unroll
    for (int mt = 0; mt < 4; mt++)
#pragma unroll
      for (int r = 0; r < 4; r++) {
        int grow = row0 + wr * 64 + mt * 16 + q * 4 + r;
        if (grow < NN) {
          size_t o = (size_t)grow * 128 + col;
          out[o] = acc2[mt][r] + bias + out[o];
        }
      }
  }
}

extern "C" void kernel_launch(void* const* d_in, const int* in_sizes, int n_in,
                              void* d_out, int out_size, void* d_ws, size_t ws_size,
                              hipStream_t stream) {
  const void* x   = d_in[0];
  const void* fcw = d_in[1];
  const void* a_l = d_in[2];
  const void* a_r = d_in[3];
  const void* lng = d_in[4];
  const void* lnb = d_in[5];
  const void* w1  = d_in[6];
  const void* b1  = d_in[7];
  const void* w2  = d_in[8];
  const void* b2  = d_in[9];
  const void* src = d_in[10];
  const void* dst = d_in[11];
  float* out = (float*)d_out;  // fp32 output

  char* ws = (char*)d_ws;
  size_t off = 0;
  auto alloc = [&](size_t bytes) -> char* {
    char* p = ws + off; off += (bytes + 255) & ~(size_t)255; return p;
  };
  int* flags            = (int*)alloc(64);   // [0,1]=float probe, [2,3]=int widths
  int* iflags           = flags + 2;
  int* cnt              = (int*)alloc((size_t)NN * 4);
  unsigned short* esrc  = (unsigned short*)alloc((size_t)NN * SLOTS * 2);
  unsigned short* canon = (unsigned short*)alloc((size_t)C_TOT * 2);
  unsigned short* z     = (unsigned short*)alloc((size_t)NN * 128 * 2);
  float* el             = (float*)alloc((size_t)NN * 8 * 4);
  float* er             = (float*)alloc((size_t)NN * 8 * 4);
  float2* mars          = (float2*)alloc((size_t)NN * 8);
  // total ≈ 36.1 MB (< verified-safe 36.5 MB)

  hipMemsetAsync(ws, 0, 256 + (size_t)NN * 4, stream);  // flags + cnt
  k_probe<<<32, 256, 0, stream>>>((const unsigned short*)x, (const int*)src, (const int*)dst, flags);
  k_convfill<<<NFA + CONVB, 256, 0, stream>>>(x, fcw, a_l, a_r, lng, lnb, w1, b1, w2, b2,
                                              flags, canon, src, dst, cnt, esrc);
  k_projfill<<<NFB + 391 * 2, 256, 0, stream>>>(canon, z, el, er, src, dst, iflags, cnt, esrc);
  k_agg<<<(NN + 3) / 4, 256, 0, stream>>>(canon, z, el, er, cnt, esrc, src, dst, iflags, out, mars);
  k_ffn<<<(NN + 127) / 128, 1024, 0, stream>>>(canon, mars, out);
}

// Round 15
// 240.728 us; speedup vs baseline: 1.0390x; 1.0390x over previous
//
#include <hip/hip_runtime.h>

#define NN 50000
#define EE 800000
#define LDK 136
#define SLOTS 64   // esrc slots per node (deg>SLOTS -> k_agg slow path)
#define FEPT 8     // edges per thread in fill
#define NFA 157    // fill blocks fused into k_convfill: edges [0, NFA*2048)
#define SPLITE (NFA * 256 * FEPT)          // 321536
#define NFB 234    // fill blocks fused into k_projfill: edges [SPLITE, EE)
#define CONVB 2048 // convert blocks

// canonical bf16 region: element offsets
#define C_X    0
#define C_ZW   6400000   // zwt[c*128+d] = fc_w[c>>4][d][c&15]
#define C_AL   6416384
#define C_AR   6416512
#define C_LNG  6416640
#define C_LNB  6416768
#define C_W1T  6416896   // w1t[n*128+k] = w1[k*512+n]
#define C_B1   6482432
#define C_W2T  6482944   // w2t[n*512+k] = w2[k*128+n]
#define C_B2   6548480
#define C_WAT  6548608   // wat[c*128+d]: c<8 -> fc_w[c]@a_l[c], c>=8 -> fc_w[c-8]@a_r[c-8]
#define C_TOT  6550656

typedef __attribute__((ext_vector_type(8))) short bf16x8;
typedef __attribute__((ext_vector_type(4))) float f32x4;

__device__ __forceinline__ float bf2f(unsigned short u) {
  union { unsigned int i; float f; } v; v.i = ((unsigned int)u) << 16; return v.f;
}
__device__ __forceinline__ unsigned short f2bf(float f) {
  union { float f; unsigned int i; } v; v.f = f;
  unsigned int r = v.i + 0x7fffu + ((v.i >> 16) & 1u);
  return (unsigned short)(r >> 16);
}
__device__ __forceinline__ int ld_idx(const void* p, int i, int is64) {
  return is64 ? (int)((const long long*)p)[i] : ((const int*)p)[i];
}

// exact-form gelu via A&S 7.1.26 erf approx (|err| <= 1.5e-7, branchless).
__device__ __forceinline__ float fast_gelu(float u) {
  float ax = fabsf(u) * 0.70710678118654752f;
  float d  = fmaf(0.3275911f, ax, 1.f);
  float r  = __builtin_amdgcn_rcpf(d);
  r = r * fmaf(-d, r, 2.f);
  float p = fmaf(1.061405429f, r, -1.453152027f);
  p = fmaf(p, r, 1.421413741f);
  p = fmaf(p, r, -0.284496736f);
  p = fmaf(p, r, 0.254829592f);
  p = p * r;
  float e = __expf(-ax * ax);
  float erfv = fmaf(-p, e, 1.f);
  union { float f; unsigned int i; } su, se;
  su.f = u; se.f = erfv;
  se.i = se.i | (su.i & 0x80000000u);
  return 0.5f * u * (1.f + se.f);
}

// ---- merged dtype probes: flags[0,1]=x float probe, flags[2,3]=src/dst widths ----
__global__ void k_probe(const unsigned short* __restrict__ xr,
                        const int* __restrict__ s, const int* __restrict__ d,
                        int* __restrict__ flags) {
  int i = blockIdx.x * 256 + threadIdx.x;
  int bad = 0, zc = 0, zs = 0, zd = 0;
  for (int j = i; j < 65536; j += 32 * 256) {
    unsigned short u = xr[j];
    if ((u & 0x7F80u) == 0x7F80u) bad = 1;
    if (((j & 1) == 0) && u == 0) zc++;
  }
  for (int j = i; j < 131072; j += 32 * 256) {
    if (j & 1) {
      if (s[j] == 0) zs++;
      if (d[j] == 0) zd++;
    }
  }
  if (bad) atomicOr(&flags[0], 1);
  if (zc) atomicAdd(&flags[1], zc);
  if (zs) atomicAdd(&flags[2], zs);
  if (zd) atomicAdd(&flags[3], zd);
}

// ---- strided-slot fill body: FEPT edges starting at base ----
__device__ __forceinline__ void do_fill(const void* __restrict__ src,
                                        const void* __restrict__ dst,
                                        const int* __restrict__ iflags,
                                        int* __restrict__ cnt,
                                        unsigned short* __restrict__ esrc,
                                        int base) {
  if (base >= EE) return;
  const int s64 = iflags[0] > 1000, d64 = iflags[1] > 1000;
  int dv[FEPT], sv[FEPT];
  if (!d64 && base + FEPT <= EE) {
    const int4* p = (const int4*)((const int*)dst + base);
    int4 a = p[0], b = p[1];
    dv[0]=a.x; dv[1]=a.y; dv[2]=a.z; dv[3]=a.w; dv[4]=b.x; dv[5]=b.y; dv[6]=b.z; dv[7]=b.w;
  } else {
#pragma unroll
    for (int j = 0; j < FEPT; j++) dv[j] = (base + j < EE) ? ld_idx(dst, base + j, d64) : 0;
  }
  if (!s64 && base + FEPT <= EE) {
    const int4* p = (const int4*)((const int*)src + base);
    int4 a = p[0], b = p[1];
    sv[0]=a.x; sv[1]=a.y; sv[2]=a.z; sv[3]=a.w; sv[4]=b.x; sv[5]=b.y; sv[6]=b.z; sv[7]=b.w;
  } else {
#pragma unroll
    for (int j = 0; j < FEPT; j++) sv[j] = (base + j < EE) ? ld_idx(src, base + j, s64) : 0;
  }
#pragma unroll
  for (int j = 0; j < FEPT; j++) {
    if (base + j < EE) {
      unsigned d = (unsigned)dv[j]; if (d >= NN) d = 0;
      unsigned s = (unsigned)sv[j]; if (s >= NN) s = 0;
      int p = atomicAdd(&cnt[d], 1);
      if (p < SLOTS) esrc[d * SLOTS + p] = (unsigned short)s;
    }
  }
}

// ---- fused: canonicalize (bf16 canon + transposes + wat) ∥ fill edges [0,SPLITE) ----
__global__ __launch_bounds__(256) void k_convfill(
    const void* __restrict__ x, const void* __restrict__ fcw,
    const void* __restrict__ a_l, const void* __restrict__ a_r,
    const void* __restrict__ lng, const void* __restrict__ lnb,
    const void* __restrict__ w1, const void* __restrict__ b1,
    const void* __restrict__ w2, const void* __restrict__ b2,
    const int* __restrict__ flags, unsigned short* __restrict__ canon,
    const void* __restrict__ srcp, const void* __restrict__ dstp,
    int* __restrict__ cnt, unsigned short* __restrict__ esrc) {
  if (blockIdx.x < NFA) {
    do_fill(srcp, dstp, flags + 2, cnt, esrc, (blockIdx.x * 256 + threadIdx.x) * FEPT);
    return;
  }
  const int isf32 = (flags[0] != 0) || (flags[1] > 8192);
  const int tid0 = (blockIdx.x - NFA) * 256 + threadIdx.x;
  // phase 1: x region, vectorized 8 elems/iter
  for (int v = tid0; v < (C_ZW >> 3); v += CONVB * 256) {
    if (isf32) {
      const float* xf = (const float*)x + v * 8;
      float4 a = *(const float4*)xf;
      float4 b = *(const float4*)(xf + 4);
      union { unsigned short u[8]; uint4 q; } pk;
      pk.u[0] = f2bf(a.x); pk.u[1] = f2bf(a.y); pk.u[2] = f2bf(a.z); pk.u[3] = f2bf(a.w);
      pk.u[4] = f2bf(b.x); pk.u[5] = f2bf(b.y); pk.u[6] = f2bf(b.z); pk.u[7] = f2bf(b.w);
      *(uint4*)(canon + v * 8) = pk.q;
    } else {
      *(uint4*)(canon + v * 8) = *(const uint4*)((const unsigned short*)x + v * 8);
    }
  }
  // phase 2: weight/bias regions (scalar) + wat fused projection vectors
  for (int i = C_ZW + tid0; i < C_TOT; i += CONVB * 256) {
    unsigned short v;
    if (i >= C_WAT) {
      int j = i - C_WAT; int c = j >> 7, dd = j & 127; int h = c & 7;
      const void* fa = (c < 8) ? a_l : a_r;
      float s = 0.f;
      if (isf32) {
        const float* fw = (const float*)fcw + h * 2048 + dd * 16;
        const float* fv = (const float*)fa + h * 16;
#pragma unroll
        for (int o = 0; o < 16; o++) s += fw[o] * fv[o];
      } else {
        const unsigned short* fw = (const unsigned short*)fcw + h * 2048 + dd * 16;
        const unsigned short* fv = (const unsigned short*)fa + h * 16;
#pragma unroll
        for (int o = 0; o < 16; o++) s += bf2f(fw[o]) * bf2f(fv[o]);
      }
      v = f2bf(s);
    } else {
      const void* src; int idx;
      if (i < C_AL)       { int j = i - C_ZW; int c = j >> 7, d = j & 127; src = fcw; idx = (c >> 4) * 2048 + d * 16 + (c & 15); }
      else if (i < C_AR)  { src = a_l; idx = i - C_AL; }
      else if (i < C_LNG) { src = a_r; idx = i - C_AR; }
      else if (i < C_LNB) { src = lng; idx = i - C_LNG; }
      else if (i < C_W1T) { src = lnb; idx = i - C_LNB; }
      else if (i < C_B1)  { int j = i - C_W1T; int n = j >> 7, k = j & 127; src = w1; idx = k * 512 + n; }
      else if (i < C_W2T) { src = b1;  idx = i - C_B1; }
      else if (i < C_B2)  { int j = i - C_W2T; int n = j >> 9, k = j & 511; src = w2; idx = k * 128 + n; }
      else                { src = b2;  idx = i - C_B2; }
      if (isf32) v = f2bf(((const float*)src)[idx]);
      else       v = ((const unsigned short*)src)[idx];
    }
    canon[i] = v;
  }
}

// ---- fused: projection z = x@W (MFMA) + el/er via wat ∥ fill edges [SPLITE,EE) ----
__global__ __launch_bounds__(256) void k_projfill(
    const unsigned short* __restrict__ canon,
    unsigned short* __restrict__ z, float* __restrict__ el, float* __restrict__ er,
    const void* __restrict__ srcp, const void* __restrict__ dstp,
    const int* __restrict__ iflags,
    int* __restrict__ cnt, unsigned short* __restrict__ esrc) {
  __shared__ unsigned short sA[128 * LDK];
  __shared__ unsigned short sB[64 * LDK];
  if (blockIdx.x < NFB) {
    do_fill(srcp, dstp, iflags, cnt, esrc,
            SPLITE + (blockIdx.x * 256 + threadIdx.x) * FEPT);
    return;
  }
  const int pid = blockIdx.x - NFB;
  const unsigned short* xc  = canon + C_X;
  const unsigned short* zwt = canon + C_ZW;
  const unsigned short* wat = canon + C_WAT;
  const int tid = threadIdx.x;
  const int row0 = (pid >> 1) * 128;
  const int n0 = (pid & 1) * 64;
  for (int v = tid; v < 2048; v += 256) {
    int r = v >> 4, k8 = (v & 15) << 3;
    int gr = row0 + r; if (gr >= NN) gr = NN - 1;
    *(uint4*)(&sA[r * LDK + k8]) = *(const uint4*)(xc + gr * 128 + k8);
  }
  for (int v = tid; v < 1024; v += 256) {
    int n = v >> 4, k8 = (v & 15) << 3;
    *(uint4*)(&sB[n * LDK + k8]) = *(const uint4*)(zwt + (n0 + n) * 128 + k8);
  }
  __syncthreads();
  const int lane = tid & 63, w = tid >> 6;
  const int mr = lane & 15, q = lane >> 4;
  const f32x4 zero = {0.f, 0.f, 0.f, 0.f};
  f32x4 acc[8];
#pragma unroll
  for (int i = 0; i < 8; i++) acc[i] = zero;
#pragma unroll
  for (int kc = 0; kc < 4; kc++) {
    bf16x8 b = *(const bf16x8*)(&sB[(w * 16 + mr) * LDK + kc * 32 + q * 8]);
#pragma unroll
    for (int mt = 0; mt < 8; mt++) {
      bf16x8 a = *(const bf16x8*)(&sA[(mt * 16 + mr) * LDK + kc * 32 + q * 8]);
      acc[mt] = __builtin_amdgcn_mfma_f32_16x16x32_bf16(a, b, acc[mt], 0, 0, 0);
    }
  }
  const int col = n0 + w * 16 + mr;
#pragma unroll
  for (int mt = 0; mt < 8; mt++) {
#pragma unroll
    for (int r = 0; r < 4; r++) {
      int grow = row0 + mt * 16 + q * 4 + r;
      if (grow < NN) z[grow * 128 + col] = f2bf(acc[mt][r]);
    }
  }
  // el/er: 16 extra cols, computed once per row-tile by the half-0 block.
  // wave w covers row-tiles {w, w+4}.
  if (n0 == 0) {
    f32x4 e0 = zero, e1 = zero;
#pragma unroll
    for (int kc = 0; kc < 4; kc++) {
      bf16x8 b = *(const bf16x8*)(wat + mr * 128 + kc * 32 + q * 8);
      bf16x8 a0 = *(const bf16x8*)(&sA[(w * 16 + mr) * LDK + kc * 32 + q * 8]);
      bf16x8 a1 = *(const bf16x8*)(&sA[((w + 4) * 16 + mr) * LDK + kc * 32 + q * 8]);
      e0 = __builtin_amdgcn_mfma_f32_16x16x32_bf16(a0, b, e0, 0, 0, 0);
      e1 = __builtin_amdgcn_mfma_f32_16x16x32_bf16(a1, b, e1, 0, 0, 0);
    }
    float* eo = (mr < 8) ? el : er;
    const int hh = mr & 7;
#pragma unroll
    for (int r = 0; r < 4; r++) {
      int g0 = row0 + w * 16 + q * 4 + r;
      int g1 = row0 + (w + 4) * 16 + q * 4 + r;
      if (g0 < NN) eo[g0 * 8 + hh] = e0[r];
      if (g1 < NN) eo[g1 * 8 + hh] = e1[r];
    }
  }
}

// ---- wave-per-node: softmax + aggregate + elu + residual -> h1 fp32 (d_out) ----
// Round-9 proven two-pass form. Also computes LN stats into mars for k_ffn.
__global__ __launch_bounds__(256) void k_agg(
    const unsigned short* __restrict__ canon, const unsigned short* __restrict__ z,
    const float* __restrict__ el, const float* __restrict__ er,
    const int* __restrict__ cnt, const unsigned short* __restrict__ esrc,
    const void* __restrict__ srcp, const void* __restrict__ dstp,
    const int* __restrict__ iflags,
    float* __restrict__ h1out, float2* __restrict__ mars) {
  const unsigned short* xc = canon + C_X;
  const int lane = threadIdx.x & 63;
  const int node = blockIdx.x * 4 + (threadIdx.x >> 6);
  if (node >= NN) return;
  const int degr = cnt[node];
  const int hl = lane & 7;   // head owned by this lane
  const int g  = lane >> 3;  // edge subgroup
  const float ern = er[node * 8 + hl];

  float m = -3.0e38f;
  float acc[16];
#pragma unroll
  for (int j = 0; j < 16; j++) acc[j] = 0.f;
  float denom = 0.f;

  if (degr <= SLOTS) {
    const int deg = degr;
    const unsigned short* eptr = esrc + node * SLOTS;
    // ---- pass 1: per-head max, 16 edges in flight ----
    for (int b = 0; b < deg; b += 16) {
      int e0 = b + g, e1 = b + g + 8;
      int c0 = (e0 < deg) ? e0 : deg - 1;
      int c1 = (e1 < deg) ? e1 : deg - 1;
      unsigned s0 = eptr[c0]; if (s0 >= NN) s0 = 0;
      unsigned s1 = eptr[c1]; if (s1 >= NN) s1 = 0;
      float t0 = el[s0 * 8 + hl] + ern;
      float t1 = el[s1 * 8 + hl] + ern;
      t0 = (t0 > 0.f) ? t0 : 0.01f * t0;
      t1 = (t1 > 0.f) ? t1 : 0.01f * t1;
      if (e0 < deg) m = fmaxf(m, t0);
      if (e1 < deg) m = fmaxf(m, t1);
    }
    m = fmaxf(m, __shfl_xor(m, 8));
    m = fmaxf(m, __shfl_xor(m, 16));
    m = fmaxf(m, __shfl_xor(m, 32));
    // ---- pass 2: weighted aggregation, 16 edges in flight ----
    for (int b = 0; b < deg; b += 16) {
      int e0 = b + g, e1 = b + g + 8;
      int c0 = (e0 < deg) ? e0 : deg - 1;
      int c1 = (e1 < deg) ? e1 : deg - 1;
      unsigned s0 = eptr[c0]; if (s0 >= NN) s0 = 0;
      unsigned s1 = eptr[c1]; if (s1 >= NN) s1 = 0;
      float t0 = el[s0 * 8 + hl] + ern;
      float t1 = el[s1 * 8 + hl] + ern;
      bf16x8 za0 = *(const bf16x8*)(z + s0 * 128 + hl * 16);
      bf16x8 za1 = *(const bf16x8*)(z + s0 * 128 + hl * 16 + 8);
      bf16x8 zb0 = *(const bf16x8*)(z + s1 * 128 + hl * 16);
      bf16x8 zb1 = *(const bf16x8*)(z + s1 * 128 + hl * 16 + 8);
      t0 = (t0 > 0.f) ? t0 : 0.01f * t0;
      t1 = (t1 > 0.f) ? t1 : 0.01f * t1;
      float ex0 = (e0 < deg) ? __expf(fminf(t0 - m, 0.f)) : 0.f;
      float ex1 = (e1 < deg) ? __expf(fminf(t1 - m, 0.f)) : 0.f;
      denom += ex0 + ex1;
#pragma unroll
      for (int j = 0; j < 8; j++) {
        acc[j]     += ex0 * bf2f((unsigned short)za0[j]) + ex1 * bf2f((unsigned short)zb0[j]);
        acc[j + 8] += ex0 * bf2f((unsigned short)za1[j]) + ex1 * bf2f((unsigned short)zb1[j]);
      }
    }
  } else {
    // ---- slow path (deg > SLOTS; statistically unreachable, kept for correctness):
    // rescan ALL raw edges, filter dst == node. 8 edges in flight.
    const int s64 = iflags[0] > 1000, d64 = iflags[1] > 1000;
    for (int b = 0; b < EE; b += 8) {
      int e = b + g;
      unsigned dd = (unsigned)ld_idx(dstp, e, d64); if (dd >= NN) dd = 0;
      bool ok = (dd == (unsigned)node);
      unsigned s0 = (unsigned)ld_idx(srcp, e, s64); if (s0 >= NN) s0 = 0;
      float t0 = el[s0 * 8 + hl] + ern;
      t0 = (t0 > 0.f) ? t0 : 0.01f * t0;
      if (ok) m = fmaxf(m, t0);
    }
    m = fmaxf(m, __shfl_xor(m, 8));
    m = fmaxf(m, __shfl_xor(m, 16));
    m = fmaxf(m, __shfl_xor(m, 32));
    for (int b = 0; b < EE; b += 8) {
      int e = b + g;
      unsigned dd = (unsigned)ld_idx(dstp, e, d64); if (dd >= NN) dd = 0;
      bool ok = (dd == (unsigned)node);
      unsigned s0 = (unsigned)ld_idx(srcp, e, s64); if (s0 >= NN) s0 = 0;
      float t0 = el[s0 * 8 + hl] + ern;
      t0 = (t0 > 0.f) ? t0 : 0.01f * t0;
      float ex0 = ok ? __expf(fminf(t0 - m, 0.f)) : 0.f;
      denom += ex0;
      bf16x8 za0 = *(const bf16x8*)(z + s0 * 128 + hl * 16);
      bf16x8 za1 = *(const bf16x8*)(z + s0 * 128 + hl * 16 + 8);
#pragma unroll
      for (int j = 0; j < 8; j++) {
        acc[j]     += ex0 * bf2f((unsigned short)za0[j]);
        acc[j + 8] += ex0 * bf2f((unsigned short)za1[j]);
      }
    }
  }

  // ---- denom reduce + cross-group reduce-scatter: 16->8->4->2 ----
  denom += __shfl_xor(denom, 8);
  denom += __shfl_xor(denom, 16);
  denom += __shfl_xor(denom, 32);
  {
    const bool hi1 = (lane & 32) != 0;   // g bit 2
#pragma unroll
    for (int j = 0; j < 8; j++) {
      float send = hi1 ? acc[j] : acc[j + 8];
      float recv = __shfl_xor(send, 32);
      float keep = hi1 ? acc[j + 8] : acc[j];
      acc[j] = keep + recv;
    }
    const bool hi2 = (lane & 16) != 0;   // g bit 1
#pragma unroll
    for (int j = 0; j < 4; j++) {
      float send = hi2 ? acc[j] : acc[j + 4];
      float recv = __shfl_xor(send, 16);
      float keep = hi2 ? acc[j + 4] : acc[j];
      acc[j] = keep + recv;
    }
    const bool hi3 = (lane & 8) != 0;    // g bit 0
#pragma unroll
    for (int j = 0; j < 2; j++) {
      float send = hi3 ? acc[j] : acc[j + 2];
      float recv = __shfl_xor(send, 8);
      float keep = hi3 ? acc[j + 2] : acc[j];
      acc[j] = keep + recv;
    }
  }
  // lane now holds cols c = hl*16 + g*2, +1 in acc[0], acc[1]
  const float inv = (denom > 0.f) ? 1.f / denom : 0.f;
  const int c = hl * 16 + g * 2;
  float r0 = acc[0] * inv;
  float r1 = acc[1] * inv;
  unsigned int xx = *(const unsigned int*)(xc + node * 128 + c);
  float hv0 = ((r0 > 0.f) ? r0 : (__expf(fminf(r0, 0.f)) - 1.f)) + bf2f((unsigned short)(xx & 0xffffu));
  float hv1 = ((r1 > 0.f) ? r1 : (__expf(fminf(r1, 0.f)) - 1.f)) + bf2f((unsigned short)(xx >> 16));
  // ---- LN stats: wave holds the full 128-col row ----
  float s1 = hv0 + hv1;
  float s2 = hv0 * hv0 + hv1 * hv1;
#pragma unroll
  for (int off = 1; off < 64; off <<= 1) {
    s1 += __shfl_xor(s1, off);
    s2 += __shfl_xor(s2, off);
  }
  if (lane == 0) {
    float mu = s1 * (1.f / 128.f);
    float var = s2 * (1.f / 128.f) - mu * mu;
    mars[node] = make_float2(mu, rsqrtf(fmaxf(var, 0.f) + 1e-6f));
  }
  *(float2*)(h1out + node * 128 + c) = make_float2(hv0, hv1);
}

// ---- fused FFN (MFMA): LN-apply -> gelu(ln@w1+b1)@w2 + b2 + h1 ----
// 64 rows/block, 512 threads (8 waves), 4 K-quarters of 128 inter cols.
// LDS 34.8 KB -> 4 blocks/CU. LN stats precomputed in k_agg (mars).
// Proven local optimum (rounds 10/13/14 tested 32/128-row variants: both worse).
__global__ __launch_bounds__(512) void k_ffn(
    const unsigned short* __restrict__ canon, const float2* __restrict__ mars,
    float* __restrict__ out) {
  const unsigned short* lngc = canon + C_LNG;
  const unsigned short* lnbc = canon + C_LNB;
  const unsigned short* w1t  = canon + C_W1T;
  const unsigned short* b1c  = canon + C_B1;
  const unsigned short* w2t  = canon + C_W2T;
  const unsigned short* b2c  = canon + C_B2;
  __shared__ unsigned short sLn[64 * LDK];   // 17408 B
  __shared__ unsigned short sInt[64 * LDK];  // 17408 B (128 cols + 8 pad)
  const int tid = threadIdx.x;
  const int row0 = blockIdx.x * 64;
  // ---- LN apply: 8 threads/row, 16 elems each ----
  {
    const int r = tid >> 3, t8 = tid & 7;
    const int grow = row0 + r;
    const int gr = (grow < NN) ? grow : NN - 1;
    const float2 ms = mars[gr];
    const float* hrow = out + (size_t)gr * 128 + t8 * 16;
#pragma unroll
    for (int h8 = 0; h8 < 2; h8++) {
      float4 a = *(const float4*)(hrow + h8 * 8);
      float4 b = *(const float4*)(hrow + h8 * 8 + 4);
      union { unsigned short u[8]; uint4 q; } gv, bv, pk;
      gv.q = *(const uint4*)(lngc + t8 * 16 + h8 * 8);
      bv.q = *(const uint4*)(lnbc + t8 * 16 + h8 * 8);
      float vv[8] = {a.x, a.y, a.z, a.w, b.x, b.y, b.z, b.w};
#pragma unroll
      for (int j = 0; j < 8; j++)
        pk.u[j] = f2bf((vv[j] - ms.x) * ms.y * bf2f(gv.u[j]) + bf2f(bv.u[j]));
      *(uint4*)(&sLn[r * LDK + t8 * 16 + h8 * 8]) = pk.q;
    }
  }
  __syncthreads();
  const int lane = tid & 63, w = tid >> 6;   // 8 waves
  const int mr = lane & 15, q = lane >> 4;
  const f32x4 zero = {0.f, 0.f, 0.f, 0.f};
  f32x4 acc2[4];
#pragma unroll
  for (int a = 0; a < 4; a++) acc2[a] = zero;
#pragma unroll
  for (int qr = 0; qr < 4; qr++) {
    if (qr) __syncthreads();   // previous quarter's sInt readers done
    // ---- GEMM1 (swapped): wave w covers inter cols [qr*128 + w*16, +16) ----
    const int colg = qr * 128 + w * 16;
    f32x4 a1[4];
#pragma unroll
    for (int a = 0; a < 4; a++) a1[a] = zero;
#pragma unroll
    for (int kc = 0; kc < 4; kc++) {
      bf16x8 wf = *(const bf16x8*)(w1t + (colg + mr) * 128 + kc * 32 + q * 8);
#pragma unroll
      for (int rt = 0; rt < 4; rt++) {
        bf16x8 lf = *(const bf16x8*)(&sLn[(rt * 16 + mr) * LDK + kc * 32 + q * 8]);
        a1[rt] = __builtin_amdgcn_mfma_f32_16x16x32_bf16(wf, lf, a1[rt], 0, 0, 0);
      }
    }
    // C[icol = colg + q*4 + r][row = rt*16 + mr]; sInt local col = w*16 + q*4
    union { unsigned short u[4]; uint2 v; } b1v;
    b1v.v = *(const uint2*)(b1c + colg + q * 4);
#pragma unroll
    for (int rt = 0; rt < 4; rt++) {
      union { unsigned short u[4]; uint2 v; } pk;
#pragma unroll
      for (int r = 0; r < 4; r++)
        pk.u[r] = f2bf(fast_gelu(a1[rt][r] + bf2f(b1v.u[r])));
      *(uint2*)(&sInt[(rt * 16 + mr) * LDK + w * 16 + q * 4]) = pk.v;
    }
    __syncthreads();
    // ---- GEMM2: K-chunk [qr*128, +128), out col = w*16 + mr ----
#pragma unroll
    for (int ks = 0; ks < 4; ks++) {
      bf16x8 bw = *(const bf16x8*)(w2t + (w * 16 + mr) * 512 + qr * 128 + ks * 32 + q * 8);
#pragma unroll
      for (int mt = 0; mt < 4; mt++) {
        bf16x8 af = *(const bf16x8*)(&sInt[(mt * 16 + mr) * LDK + ks * 32 + q * 8]);
        acc2[mt] = __builtin_amdgcn_mfma_f32_16x16x32_bf16(af, bw, acc2[mt], 0, 0, 0);
      }
    }
  }
  {
    const int col = w * 16 + mr;
    const float bias = bf2f(b2c[col]);
#pragma unroll
    for (int mt = 0; mt < 4; mt++)
#pragma unroll
      for (int r = 0; r < 4; r++) {
        int grow = row0 + mt * 16 + q * 4 + r;
        if (grow < NN) {
          size_t o = (size_t)grow * 128 + col;
          out[o] = acc2[mt][r] + bias + out[o];
        }
      }
  }
}

extern "C" void kernel_launch(void* const* d_in, const int* in_sizes, int n_in,
                              void* d_out, int out_size, void* d_ws, size_t ws_size,
                              hipStream_t stream) {
  const void* x   = d_in[0];
  const void* fcw = d_in[1];
  const void* a_l = d_in[2];
  const void* a_r = d_in[3];
  const void* lng = d_in[4];
  const void* lnb = d_in[5];
  const void* w1  = d_in[6];
  const void* b1  = d_in[7];
  const void* w2  = d_in[8];
  const void* b2  = d_in[9];
  const void* src = d_in[10];
  const void* dst = d_in[11];
  float* out = (float*)d_out;  // fp32 output

  char* ws = (char*)d_ws;
  size_t off = 0;
  auto alloc = [&](size_t bytes) -> char* {
    char* p = ws + off; off += (bytes + 255) & ~(size_t)255; return p;
  };
  int* flags            = (int*)alloc(64);   // [0,1]=float probe, [2,3]=int widths
  int* iflags           = flags + 2;
  int* cnt              = (int*)alloc((size_t)NN * 4);
  unsigned short* esrc  = (unsigned short*)alloc((size_t)NN * SLOTS * 2);
  unsigned short* canon = (unsigned short*)alloc((size_t)C_TOT * 2);
  unsigned short* z     = (unsigned short*)alloc((size_t)NN * 128 * 2);
  float* el             = (float*)alloc((size_t)NN * 8 * 4);
  float* er             = (float*)alloc((size_t)NN * 8 * 4);
  float2* mars          = (float2*)alloc((size_t)NN * 8);
  // total ≈ 36.1 MB (< verified-safe 36.5 MB)

  hipMemsetAsync(ws, 0, 256 + (size_t)NN * 4, stream);  // flags + cnt
  k_probe<<<32, 256, 0, stream>>>((const unsigned short*)x, (const int*)src, (const int*)dst, flags);
  k_convfill<<<NFA + CONVB, 256, 0, stream>>>(x, fcw, a_l, a_r, lng, lnb, w1, b1, w2, b2,
                                              flags, canon, src, dst, cnt, esrc);
  k_projfill<<<NFB + 391 * 2, 256, 0, stream>>>(canon, z, el, er, src, dst, iflags, cnt, esrc);
  k_agg<<<(NN + 3) / 4, 256, 0, stream>>>(canon, z, el, er, cnt, esrc, src, dst, iflags, out, mars);
  k_ffn<<<(NN + 63) / 64, 512, 0, stream>>>(canon, mars, out);
}